// Round 10
// baseline (97.486 us; speedup 1.0000x reference)
//
#include <hip/hip_runtime.h>
#include <math.h>

#define C_ 512
#define D_ 256
#define KS_ 4
#define TOPK_ 10
#define NEG 1e20f

typedef float v2f __attribute__((ext_vector_type(2)));
typedef float v4f __attribute__((ext_vector_type(4)));

__device__ __forceinline__ int csw2(int g) { return g ^ ((g >> 3) & 1); }

#define ASTR 36     // a_s row stride: %4==0 -> b128 reads aligned; 36%32=4 -> transposed writes conflict-free
#define BSTR2 260   // b_s row stride: %4==0 -> b128 reads aligned; 260%32=4 -> transposed writes 2-way max
#define ABUF2 (16 * ASTR)
#define BBUF2 (16 * BSTR2)

// pk-FMA with A-half broadcast via op_sel (no splat movs). Each 32-bit half is an
// independent IEEE fp32 FMA chain -> kk-sequential accumulation stays bit-exact.
#define PKFMA_LO(ACC, AP, BP) \
    asm("v_pk_fma_f32 %0, %1, %2, %0 op_sel:[0,0,0] op_sel_hi:[0,1,1]" \
        : "+v"(ACC) : "v"(AP), "v"(BP));
#define PKFMA_HI(ACC, AP, BP) \
    asm("v_pk_fma_f32 %0, %1, %2, %0 op_sel:[1,0,0] op_sel_hi:[1,1,1]" \
        : "+v"(ACC) : "v"(AP), "v"(BP));

// ============================ Kernel 1: GEMM =============================
// attention[bt][c][e] -> ws. Tile 32x256, grid 1024 (4 blocks/CU), 8x4 acc.
// Double-buffered LDS k-slices, ONE barrier per kt; loads issued at top of kt,
// ds_writes float between FMA kk0-9 and kk10-15 (no barrier wedge).
extern "C" __global__ __launch_bounds__(256, 2)
void gemm_attn(const float* __restrict__ ctx,
               const float* __restrict__ W,
               float* __restrict__ ws)
{
    __shared__ __align__(16) float wbar_s[D_];
    __shared__ __align__(16) float a_s[2 * ABUF2];    // dbuf [kk][row 0..31] (x wbar)
    __shared__ __align__(16) float b_s[2 * BBUF2];    // dbuf [kk][col 0..255]

    const int tid  = threadIdx.x;
    const int lane = tid & 63;
    const int wv   = tid >> 6;
    const int wr   = (wv >> 1) * 16;     // wave row base
    const int wc   = (wv & 1) * 128;     // wave col base
    const int rg   = lane >> 5;
    const int cg   = lane & 31;

    // XCD swizzle: the 32 tiles of one ctx[b,t] panel land on one XCD's L2
    const int blk  = blockIdx.x;
    const int bt   = (blk & 7) * 4 + ((blk >> 3) & 3);   // 0..31
    const int tile = blk >> 5;                           // 0..31
    const int c0   = (tile & 15) * 32;
    const int n0   = (tile >> 4) * 256;

    const float* ctx_bt = ctx + (size_t)bt * (C_ * D_);

    // wbar = mean_p relu(W[p,:])
    {
        float w0 = W[tid], w1 = W[D_ + tid], w2 = W[2 * D_ + tid], w3 = W[3 * D_ + tid];
        wbar_s[tid] = 0.25f * (fmaxf(w0, 0.f) + fmaxf(w1, 0.f) + fmaxf(w2, 0.f) + fmaxf(w3, 0.f));
    }

    // staging geometry (coalesced 64B 4-lane groups, R9 shape)
    const int bcol = tid >> 2;
    const int bq   = tid & 3;
    const float* bsrc = ctx_bt + (size_t)(n0 + bcol) * D_ + bq * 4;   // + i*64*D_ + kt*16
    const int bwoff = (4 * bq) * BSTR2 + bcol;
    const int ar_ = tid >> 2;            // valid when tid<128
    const int aq  = tid & 3;
    const float* asrc = ctx_bt + (size_t)(c0 + ar_) * D_ + aq * 4;
    const int awoff = (4 * aq) * ASTR + ar_;
    const int abase = wr + rg * 8;
    const int bbase = wc + cg * 4;

    __syncthreads();   // wbar ready

    // prologue: stage slice 0 -> buffer 0
    {
        v4f B0 = *(const v4f*)(bsrc + (size_t)0 * 64 * D_);
        v4f B1 = *(const v4f*)(bsrc + (size_t)1 * 64 * D_);
        v4f B2 = *(const v4f*)(bsrc + (size_t)2 * 64 * D_);
        v4f B3 = *(const v4f*)(bsrc + (size_t)3 * 64 * D_);
        #pragma unroll
        for (int j = 0; j < 4; ++j) {
            b_s[bwoff + j * BSTR2 + 0 * 64] = B0[j];
            b_s[bwoff + j * BSTR2 + 1 * 64] = B1[j];
            b_s[bwoff + j * BSTR2 + 2 * 64] = B2[j];
            b_s[bwoff + j * BSTR2 + 3 * 64] = B3[j];
        }
        if (tid < 128) {
            v4f A0 = *(const v4f*)asrc;
            v4f wb = *(const v4f*)(wbar_s + aq * 4);
            a_s[awoff + 0 * ASTR] = A0[0] * wb[0];
            a_s[awoff + 1 * ASTR] = A0[1] * wb[1];
            a_s[awoff + 2 * ASTR] = A0[2] * wb[2];
            a_s[awoff + 3 * ASTR] = A0[3] * wb[3];
        }
    }
    __syncthreads();

    v2f acc2[8][2];
    #pragma unroll
    for (int j = 0; j < 8; ++j) { acc2[j][0] = (v2f){0.f, 0.f}; acc2[j][1] = (v2f){0.f, 0.f}; }

    // FMA over kk in [K0,K1): accumulation order kk-sequential -> bit-exact
    #define FMA_RANGE(K0, K1)                                                 \
        _Pragma("unroll")                                                     \
        for (int kk = (K0); kk < (K1); ++kk) {                                \
            v4f av0 = *(const v4f*)(acur + kk * ASTR + abase);                \
            v4f av1 = *(const v4f*)(acur + kk * ASTR + abase + 4);            \
            v4f bv  = *(const v4f*)(bcur + kk * BSTR2 + bbase);               \
            v2f a01 = __builtin_shufflevector(av0, av0, 0, 1);                \
            v2f a23 = __builtin_shufflevector(av0, av0, 2, 3);                \
            v2f a45 = __builtin_shufflevector(av1, av1, 0, 1);                \
            v2f a67 = __builtin_shufflevector(av1, av1, 2, 3);                \
            v2f blo = __builtin_shufflevector(bv, bv, 0, 1);                  \
            v2f bhi = __builtin_shufflevector(bv, bv, 2, 3);                  \
            PKFMA_LO(acc2[0][0], a01, blo)  PKFMA_LO(acc2[0][1], a01, bhi)    \
            PKFMA_HI(acc2[1][0], a01, blo)  PKFMA_HI(acc2[1][1], a01, bhi)    \
            PKFMA_LO(acc2[2][0], a23, blo)  PKFMA_LO(acc2[2][1], a23, bhi)    \
            PKFMA_HI(acc2[3][0], a23, blo)  PKFMA_HI(acc2[3][1], a23, bhi)    \
            PKFMA_LO(acc2[4][0], a45, blo)  PKFMA_LO(acc2[4][1], a45, bhi)    \
            PKFMA_HI(acc2[5][0], a45, blo)  PKFMA_HI(acc2[5][1], a45, bhi)    \
            PKFMA_LO(acc2[6][0], a67, blo)  PKFMA_LO(acc2[6][1], a67, bhi)    \
            PKFMA_HI(acc2[7][0], a67, blo)  PKFMA_HI(acc2[7][1], a67, bhi)    \
        }

    for (int kt = 0; kt < 16; ++kt) {
        const float* acur = a_s + (kt & 1) * ABUF2;
        const float* bcur = b_s + (kt & 1) * BBUF2;
        float* anx = a_s + ((kt & 1) ^ 1) * ABUF2;
        float* bnx = b_s + ((kt & 1) ^ 1) * BBUF2;
        const bool pf = (kt < 15);

        v4f B0, B1, B2, B3, A0;
        if (pf) {            // issue next-slice loads at top; latency hides under kk0-9
            const float* nb = bsrc + (kt + 1) * 16;
            B0 = *(const v4f*)(nb + (size_t)0 * 64 * D_);
            B1 = *(const v4f*)(nb + (size_t)1 * 64 * D_);
            B2 = *(const v4f*)(nb + (size_t)2 * 64 * D_);
            B3 = *(const v4f*)(nb + (size_t)3 * 64 * D_);
            if (tid < 128) A0 = *(const v4f*)(asrc + (kt + 1) * 16);
        }
        FMA_RANGE(0, 10)
        if (pf) {            // writes to the other buffer: no barrier needed here
            #pragma unroll
            for (int j = 0; j < 4; ++j) {
                bnx[bwoff + j * BSTR2 + 0 * 64] = B0[j];
                bnx[bwoff + j * BSTR2 + 1 * 64] = B1[j];
                bnx[bwoff + j * BSTR2 + 2 * 64] = B2[j];
                bnx[bwoff + j * BSTR2 + 3 * 64] = B3[j];
            }
            if (tid < 128) {
                v4f wb = *(const v4f*)(wbar_s + (kt + 1) * 16 + aq * 4);
                anx[awoff + 0 * ASTR] = A0[0] * wb[0];
                anx[awoff + 1 * ASTR] = A0[1] * wb[1];
                anx[awoff + 2 * ASTR] = A0[2] * wb[2];
                anx[awoff + 3 * ASTR] = A0[3] * wb[3];
            }
        }
        FMA_RANGE(10, 16)
        __syncthreads();     // publishes buf^1 writes; retires buf readers
    }
    #undef FMA_RANGE

    // write 8 rows x 4 cols (b128, coalesced 512B per half-wave)
    #pragma unroll
    for (int j = 0; j < 8; ++j) {
        v4f o = __builtin_shufflevector(acc2[j][0], acc2[j][1], 0, 1, 2, 3);
        *(v4f*)(ws + ((size_t)bt * C_ + c0 + wr + rg * 8 + j) * C_ + n0 + bbase) = o;
    }
}

// ========================== Kernel 2: epilogue ===========================
extern "C" __global__ __launch_bounds__(256, 2)
void epilogue_k(const float* __restrict__ ws,
                const int* __restrict__ cmask,
                const float* __restrict__ mu_g,
                const float* __restrict__ pr_g,
                float* __restrict__ out)
{
    const int tid  = threadIdx.x;
    const int lane = tid & 63;
    const int wv   = tid >> 6;

    const int blk = blockIdx.x;
    const int bt  = blk >> 7;          // 0..31
    const int rq  = blk & 127;         // 4-row group
    const int b   = bt >> 3;

    // zero this block's output slice (fire-and-forget; drained at the barrier
    // below, covered by the top-k compute)
    {
        const float4 z = make_float4(0.f, 0.f, 0.f, 0.f);
        #pragma unroll
        for (int ks = 0; ks < KS_; ++ks) {
            float* ob = out + ((size_t)(bt * KS_ + ks) * C_ + rq * 4) * C_;
            *(float4*)(ob + (size_t)tid * 4)         = z;
            *(float4*)(ob + (size_t)(tid + 256) * 4) = z;
        }
    }

    const int c  = rq * 4 + wv;        // this wave's row
    const int vr = cmask[b * C_ + c];

    float row[8];
    {
        const float* wrow = ws + ((size_t)bt * C_ + c) * C_ + lane * 8;
        float4 r0 = *(const float4*)wrow;
        float4 r1 = *(const float4*)(wrow + 4);
        row[0] = r0.x; row[1] = r0.y; row[2] = r0.z; row[3] = r0.w;
        row[4] = r1.x; row[5] = r1.y; row[6] = r1.z; row[7] = r1.w;
        int4 m0 = *(const int4*)(cmask + b * C_ + lane * 8);
        int4 m1 = *(const int4*)(cmask + b * C_ + lane * 8 + 4);
        int em[8] = {m0.x, m0.y, m0.z, m0.w, m1.x, m1.y, m1.z, m1.w};
        #pragma unroll
        for (int i = 0; i < 8; ++i) {
            bool ok = (vr > 0) && (em[i] > 0);
            row[i] = ok ? row[i] : -NEG;
        }
    }

    float tv[TOPK_];
    int   te[TOPK_];
    unsigned int taken = 0;
    #pragma unroll
    for (int j = 0; j < TOPK_; ++j) {
        float lv = -3.3e38f;
        int   li = 0;
        #pragma unroll
        for (int i = 0; i < 8; ++i) {
            bool better = (!((taken >> i) & 1u)) && (row[i] > lv);
            lv = better ? row[i] : lv;
            li = better ? i : li;
        }
        int le = lane * 8 + li;
        #pragma unroll
        for (int off = 1; off < 64; off <<= 1) {
            float ov = __shfl_xor(lv, off);
            int   oe = __shfl_xor(le, off);
            bool take = (ov > lv) || (ov == lv && oe < le);
            lv = take ? ov : lv;
            le = take ? oe : le;
        }
        tv[j] = lv;
        te[j] = le;
        if ((le >> 3) == lane) taken |= 1u << (le & 7);
    }
    const float mx = tv[0];
    float ssum = 0.f;
    #pragma unroll
    for (int j = 0; j < TOPK_; ++j) ssum += expf(tv[j] - mx);

    float oval = 0.f;
    size_t ooff = 0;
    {
        const int ksq = (lane < 40) ? (lane / 10) : 3;
        const int myj = (lane < 40) ? (lane - (lane / 10) * 10) : 0;
        const float mu = mu_g[ksq];
        const float pr = pr_g[ksq];
        float sps = 0.f, spj = 0.f, tvj = 0.f;
        int ej = 0;
        #pragma unroll
        for (int j = 0; j < TOPK_; ++j) {
            float d = fabsf((float)(te[j] - c));
            d = fminf(d, 160.f) * (1.0f / 160.0f);
            float x  = d - mu;
            float sp = expf(-0.5f * x * x * pr * pr);
            sps += sp;
            if (j == myj) { spj = sp; tvj = tv[j]; ej = te[j]; }
        }
        oval = (expf(tvj - mx) / ssum) * (spj / sps);
        ooff = ((size_t)(bt * KS_ + ksq) * C_ + c) * C_ + ej;
    }

    __syncthreads();   // drain zero-stores (overlapped by compute above)
    if (lane < 40) out[ooff] = oval;
}

// ===================== Fallback: fused kernel (R6) =======================
#define BSTR 516
extern "C" __global__ __launch_bounds__(256, 2)
void graph_learner(const float* __restrict__ ctx,
                   const int* __restrict__ cmask,
                   const float* __restrict__ W,
                   const float* __restrict__ mu_g,
                   const float* __restrict__ pr_g,
                   float* __restrict__ out)
{
    __shared__ __align__(16) float wbar_s[D_];
    __shared__ __align__(16) float a_s[16 * ASTR];
    __shared__ __align__(16) float b_s[16 * BSTR];
    __shared__ __align__(8)  float res_s[2560];
    __shared__ unsigned int vmask_s[16];

    const int tid  = threadIdx.x;
    const int lane = tid & 63;
    const int wv   = tid >> 6;
    const int w8   = wv * 8;

    const int blk = blockIdx.x;
    const int bt  = (blk & 7) * 4 + ((blk >> 3) & 3);
    const int c0  = (blk >> 5) * 32;
    const int b   = bt >> 3;

    const float* ctx_bt = ctx + (size_t)bt * (C_ * D_);
    const int*   mask_b = cmask + b * C_;

    {
        float w0 = W[tid], w1 = W[D_ + tid], w2 = W[2 * D_ + tid], w3 = W[3 * D_ + tid];
        wbar_s[tid] = 0.25f * (fmaxf(w0, 0.f) + fmaxf(w1, 0.f) + fmaxf(w2, 0.f) + fmaxf(w3, 0.f));
    }
    if (tid < 16) {
        unsigned int m = 0;
        for (int i = 0; i < 32; ++i)
            m |= (mask_b[tid * 32 + i] > 0 ? 1u : 0u) << i;
        vmask_s[tid] = m;
    }

    const int brow = tid >> 2;
    const int bq   = tid & 3;
    const float* bsrc = ctx_bt + (size_t)brow * D_ + bq * 4;
    const int bwbase = (4 * bq) * BSTR + 4 * csw2(brow >> 2) + (brow & 3);
    const int ar_ = tid >> 2;
    const int aq  = tid & 3;
    const float* asrc = ctx_bt + (size_t)(c0 + ar_) * D_ + aq * 4;
    const int awbase = (4 * aq) * ASTR + ar_;
    const int bc0 = 4 * csw2(2 * lane);
    const int bc1 = 4 * csw2(2 * lane + 1);

    v2f acc2[8][4];
    #pragma unroll
    for (int j = 0; j < 8; ++j)
        #pragma unroll
        for (int t = 0; t < 4; ++t) acc2[j][t] = (v2f){0.f, 0.f};

    for (int kt = 0; kt < 16; ++kt) {
        __syncthreads();
        #pragma unroll
        for (int i = 0; i < 8; ++i) {
            float4 v = *(const float4*)(bsrc + (size_t)i * 64 * D_ + kt * 16);
            b_s[bwbase + 0 * BSTR + i * 64] = v.x;
            b_s[bwbase + 1 * BSTR + i * 64] = v.y;
            b_s[bwbase + 2 * BSTR + i * 64] = v.z;
            b_s[bwbase + 3 * BSTR + i * 64] = v.w;
        }
        if (tid < 128) {
            float4 v  = *(const float4*)(asrc + kt * 16);
            float4 wb = *(const float4*)(wbar_s + kt * 16 + aq * 4);
            a_s[awbase + 0 * ASTR] = v.x * wb.x;
            a_s[awbase + 1 * ASTR] = v.y * wb.y;
            a_s[awbase + 2 * ASTR] = v.z * wb.z;
            a_s[awbase + 3 * ASTR] = v.w * wb.w;
        }
        __syncthreads();
        #pragma unroll
        for (int kk = 0; kk < 16; ++kk) {
            float4 av0 = *(const float4*)(a_s + kk * ASTR + w8);
            float4 av1 = *(const float4*)(a_s + kk * ASTR + w8 + 4);
            float4 bv0 = *(const float4*)(b_s + kk * BSTR + bc0);
            float4 bv1 = *(const float4*)(b_s + kk * BSTR + bc1);
            v2f b20 = (v2f){bv0.x, bv0.y};
            v2f b21 = (v2f){bv0.z, bv0.w};
            v2f b22 = (v2f){bv1.x, bv1.y};
            v2f b23 = (v2f){bv1.z, bv1.w};
            float ar8[8] = {av0.x, av0.y, av0.z, av0.w, av1.x, av1.y, av1.z, av1.w};
            #pragma unroll
            for (int j = 0; j < 8; ++j) {
                v2f a2 = (v2f){ar8[j], ar8[j]};
                asm("v_pk_fma_f32 %0, %1, %2, %0" : "+v"(acc2[j][0]) : "v"(a2), "v"(b20));
                asm("v_pk_fma_f32 %0, %1, %2, %0" : "+v"(acc2[j][1]) : "v"(a2), "v"(b21));
                asm("v_pk_fma_f32 %0, %1, %2, %0" : "+v"(acc2[j][2]) : "v"(a2), "v"(b22));
                asm("v_pk_fma_f32 %0, %1, %2, %0" : "+v"(acc2[j][3]) : "v"(a2), "v"(b23));
            }
        }
    }

    {
        const float4 z = make_float4(0.f, 0.f, 0.f, 0.f);
        #pragma unroll
        for (int ks = 0; ks < KS_; ++ks) {
            float* ob = out + ((size_t)(bt * KS_ + ks) * C_ + c0) * C_;
            #pragma unroll
            for (int i = 0; i < 16; ++i)
                *(float4*)(ob + (size_t)(tid + i * 256) * 4) = z;
        }
    }

    const unsigned int em8 = (vmask_s[lane >> 2] >> ((lane & 3) * 8)) & 0xffu;
    const float mu0 = mu_g[0], mu1 = mu_g[1], mu2 = mu_g[2], mu3 = mu_g[3];
    const float pr0 = pr_g[0], pr1 = pr_g[1], pr2 = pr_g[2], pr3 = pr_g[3];

    #pragma unroll
    for (int jr = 0; jr < 8; ++jr) {
        const int c  = c0 + w8 + jr;
        const int vr = mask_b[c];
        float row[8];
        #pragma unroll
        for (int t = 0; t < 4; ++t) { row[2 * t] = acc2[jr][t].x; row[2 * t + 1] = acc2[jr][t].y; }
        #pragma unroll
        for (int i = 0; i < 8; ++i) {
            bool ok = (vr > 0) && ((em8 >> i) & 1u);
            row[i] = ok ? row[i] : -NEG;
        }
        float tv[TOPK_];
        int   te[TOPK_];
        unsigned int taken = 0;
        #pragma unroll
        for (int j = 0; j < TOPK_; ++j) {
            float lv = -3.3e38f;
            int   li = 0;
            #pragma unroll
            for (int i = 0; i < 8; ++i) {
                bool better = (!((taken >> i) & 1u)) && (row[i] > lv);
                lv = better ? row[i] : lv;
                li = better ? i : li;
            }
            int le = lane * 8 + li;
            #pragma unroll
            for (int off = 1; off < 64; off <<= 1) {
                float ov = __shfl_xor(lv, off);
                int   oe = __shfl_xor(le, off);
                bool take = (ov > lv) || (ov == lv && oe < le);
                lv = take ? ov : lv;
                le = take ? oe : le;
            }
            tv[j] = lv;
            te[j] = le;
            if ((le >> 3) == lane) taken |= 1u << (le & 7);
        }
        const float mx = tv[0];
        float ssum = 0.f;
        #pragma unroll
        for (int j = 0; j < TOPK_; ++j) ssum += expf(tv[j] - mx);

        if (lane < 40) {
            const int ksq = lane / 10;
            const int myj = lane - ksq * 10;
            const float mu = (ksq == 0) ? mu0 : (ksq == 1) ? mu1 : (ksq == 2) ? mu2 : mu3;
            const float pr = (ksq == 0) ? pr0 : (ksq == 1) ? pr1 : (ksq == 2) ? pr2 : pr3;
            float sps = 0.f, spj = 0.f, tvj = 0.f;
            int ej = 0;
            #pragma unroll
            for (int j = 0; j < TOPK_; ++j) {
                float d = fabsf((float)(te[j] - c));
                d = fminf(d, 160.f) * (1.0f / 160.0f);
                float x  = d - mu;
                float sp = expf(-0.5f * x * x * pr * pr);
                sps += sp;
                if (j == myj) { spj = sp; tvj = tv[j]; ej = te[j]; }
            }
            float val = (expf(tvj - mx) / ssum) * (spj / sps);
            int   off = ((bt * KS_ + ksq) * C_ + c) * C_ + ej;
            int   slot = (((wv * 8 + jr) * 40) + lane) * 2;
            res_s[slot]     = val;
            res_s[slot + 1] = __int_as_float(off);
        }
    }

    __syncthreads();
    #pragma unroll
    for (int i = 0; i < 5; ++i) {
        int p = tid * 5 + i;
        float v   = res_s[2 * p];
        int   off = __float_as_int(res_s[2 * p + 1]);
        out[off] = v;
    }
}

extern "C" void kernel_launch(void* const* d_in, const int* in_sizes, int n_in,
                              void* d_out, int out_size, void* d_ws, size_t ws_size,
                              hipStream_t stream) {
    (void)in_sizes; (void)n_in; (void)out_size;
    const float* ctx   = (const float*)d_in[0];
    const int*   cmask = (const int*)d_in[1];
    const float* W     = (const float*)d_in[2];
    const float* mu    = (const float*)d_in[3];
    const float* pr    = (const float*)d_in[4];
    const size_t WS_NEEDED = (size_t)32 * C_ * C_ * sizeof(float);   // 33.5 MB
    if (ws_size >= WS_NEEDED) {
        float* ws = (float*)d_ws;
        gemm_attn<<<dim3(1024), dim3(256), 0, stream>>>(ctx, W, ws);
        epilogue_k<<<dim3(4096), dim3(256), 0, stream>>>(ws, cmask, mu, pr, (float*)d_out);
    } else {
        graph_learner<<<dim3(512), dim3(256), 0, stream>>>(ctx, cmask, W, mu, pr, (float*)d_out);
    }
}

// Round 11
// 94.997 us; speedup vs baseline: 1.0262x; 1.0262x over previous
//
#include <hip/hip_runtime.h>
#include <math.h>

#define C_ 512
#define D_ 256
#define KS_ 4
#define TOPK_ 10
#define NEG 1e20f

typedef float v2f __attribute__((ext_vector_type(2)));
typedef float v4f __attribute__((ext_vector_type(4)));

__device__ __forceinline__ int csw2(int g) { return g ^ ((g >> 3) & 1); }

#define ASTR 36     // fused-kernel a_s stride
#define ASTR3 68    // gemm a_s stride: %4==0 -> b128 aligned; 68%32=4 -> staged writes 2-way
#define BSTR2 260   // gemm b_s stride: %4==0 -> b128 aligned; 260%32=4 -> staged writes 2-way
#define ABUF3 (16 * ASTR3)
#define BBUF3 (16 * BSTR2)

// pk-FMA with A-half broadcast via op_sel. Each 32-bit half is an independent
// IEEE fp32 FMA chain -> kk-sequential accumulation stays bit-exact.
#define PKFMA_LO(ACC, AP, BP) \
    asm("v_pk_fma_f32 %0, %1, %2, %0 op_sel:[0,0,0] op_sel_hi:[0,1,1]" \
        : "+v"(ACC) : "v"(AP), "v"(BP));
#define PKFMA_HI(ACC, AP, BP) \
    asm("v_pk_fma_f32 %0, %1, %2, %0 op_sel:[1,0,0] op_sel_hi:[1,1,1]" \
        : "+v"(ACC) : "v"(AP), "v"(BP));

// ============================ Kernel 1: GEMM =============================
// attention[bt][c][e] -> ws. Tile 64x256, grid 512 (2 blocks/CU), 8x8 acc
// (0.5 LDS-B/FLOP vs R10's 0.75 -- the measured LDS-return roofline).
// R10's dbuf one-barrier schedule. kk-sequential fp32 -> bit-identical.
extern "C" __global__ __launch_bounds__(256, 2)
void gemm_attn(const float* __restrict__ ctx,
               const float* __restrict__ W,
               float* __restrict__ ws)
{
    __shared__ __align__(16) float wbar_s[D_];
    __shared__ __align__(16) float a_s[2 * ABUF3];    // dbuf [kk][row 0..63] (x wbar)
    __shared__ __align__(16) float b_s[2 * BBUF3];    // dbuf [kk][col 0..255]

    const int tid  = threadIdx.x;
    const int lane = tid & 63;
    const int wv   = tid >> 6;
    const int wr   = (wv >> 1) * 32;     // wave row base (0/32)
    const int wc   = (wv & 1) * 128;     // wave col base (0/128)
    const int rg   = lane >> 4;          // row-group 0..3
    const int cg   = lane & 15;          // col-group 0..15

    // XCD swizzle: the 16 tiles of one ctx[b,t] panel land on one XCD's L2
    const int blk  = blockIdx.x;
    const int bt   = (blk & 7) * 4 + ((blk >> 3) & 3);   // 0..31
    const int tile = blk >> 5;                           // 0..15
    const int c0   = (tile & 7) * 64;                    // row tile
    const int n0   = (tile >> 3) * 256;                  // col tile

    const float* ctx_bt = ctx + (size_t)bt * (C_ * D_);

    // wbar = mean_p relu(W[p,:])
    {
        float w0 = W[tid], w1 = W[D_ + tid], w2 = W[2 * D_ + tid], w3 = W[3 * D_ + tid];
        wbar_s[tid] = 0.25f * (fmaxf(w0, 0.f) + fmaxf(w1, 0.f) + fmaxf(w2, 0.f) + fmaxf(w3, 0.f));
    }

    // staging geometry (coalesced 64B 4-lane groups)
    const int bcol = tid >> 2;           // 0..63; +i*64, i=0..3
    const int bq   = tid & 3;
    const float* bsrc = ctx_bt + (size_t)(n0 + bcol) * D_ + bq * 4;
    const int bwoff = (4 * bq) * BSTR2 + bcol;
    const int ar_ = tid >> 2;            // 0..63 (all threads stage A now)
    const int aq  = tid & 3;
    const float* asrc = ctx_bt + (size_t)(c0 + ar_) * D_ + aq * 4;
    const int awoff = (4 * aq) * ASTR3 + ar_;
    // compute read bases
    const int abase = wr + rg * 8;
    const int bbase = wc + cg * 4;       // quad 0; quad 1 at +64

    __syncthreads();   // wbar ready

    // prologue: stage slice 0 -> buffer 0
    {
        v4f B0 = *(const v4f*)(bsrc + (size_t)0 * 64 * D_);
        v4f B1 = *(const v4f*)(bsrc + (size_t)1 * 64 * D_);
        v4f B2 = *(const v4f*)(bsrc + (size_t)2 * 64 * D_);
        v4f B3 = *(const v4f*)(bsrc + (size_t)3 * 64 * D_);
        v4f A0 = *(const v4f*)asrc;
        #pragma unroll
        for (int j = 0; j < 4; ++j) {
            b_s[bwoff + j * BSTR2 + 0 * 64] = B0[j];
            b_s[bwoff + j * BSTR2 + 1 * 64] = B1[j];
            b_s[bwoff + j * BSTR2 + 2 * 64] = B2[j];
            b_s[bwoff + j * BSTR2 + 3 * 64] = B3[j];
        }
        v4f wb = *(const v4f*)(wbar_s + aq * 4);
        a_s[awoff + 0 * ASTR3] = A0[0] * wb[0];
        a_s[awoff + 1 * ASTR3] = A0[1] * wb[1];
        a_s[awoff + 2 * ASTR3] = A0[2] * wb[2];
        a_s[awoff + 3 * ASTR3] = A0[3] * wb[3];
    }
    __syncthreads();

    v2f acc2[8][4];   // [row j][col pair t]: t=0,1 -> cols bbase..+3 ; t=2,3 -> bbase+64..+67
    #pragma unroll
    for (int j = 0; j < 8; ++j)
        #pragma unroll
        for (int t = 0; t < 4; ++t) acc2[j][t] = (v2f){0.f, 0.f};

    #define FMA_RANGE(K0, K1)                                                 \
        _Pragma("unroll")                                                     \
        for (int kk = (K0); kk < (K1); ++kk) {                                \
            v4f av0 = *(const v4f*)(acur + kk * ASTR3 + abase);               \
            v4f av1 = *(const v4f*)(acur + kk * ASTR3 + abase + 4);           \
            v4f bv0 = *(const v4f*)(bcur + kk * BSTR2 + bbase);               \
            v4f bv1 = *(const v4f*)(bcur + kk * BSTR2 + bbase + 64);          \
            v2f a01 = __builtin_shufflevector(av0, av0, 0, 1);                \
            v2f a23 = __builtin_shufflevector(av0, av0, 2, 3);                \
            v2f a45 = __builtin_shufflevector(av1, av1, 0, 1);                \
            v2f a67 = __builtin_shufflevector(av1, av1, 2, 3);                \
            v2f b0l = __builtin_shufflevector(bv0, bv0, 0, 1);                \
            v2f b0h = __builtin_shufflevector(bv0, bv0, 2, 3);                \
            v2f b1l = __builtin_shufflevector(bv1, bv1, 0, 1);                \
            v2f b1h = __builtin_shufflevector(bv1, bv1, 2, 3);                \
            PKFMA_LO(acc2[0][0], a01, b0l) PKFMA_LO(acc2[0][1], a01, b0h)     \
            PKFMA_LO(acc2[0][2], a01, b1l) PKFMA_LO(acc2[0][3], a01, b1h)     \
            PKFMA_HI(acc2[1][0], a01, b0l) PKFMA_HI(acc2[1][1], a01, b0h)     \
            PKFMA_HI(acc2[1][2], a01, b1l) PKFMA_HI(acc2[1][3], a01, b1h)     \
            PKFMA_LO(acc2[2][0], a23, b0l) PKFMA_LO(acc2[2][1], a23, b0h)     \
            PKFMA_LO(acc2[2][2], a23, b1l) PKFMA_LO(acc2[2][3], a23, b1h)     \
            PKFMA_HI(acc2[3][0], a23, b0l) PKFMA_HI(acc2[3][1], a23, b0h)     \
            PKFMA_HI(acc2[3][2], a23, b1l) PKFMA_HI(acc2[3][3], a23, b1h)     \
            PKFMA_LO(acc2[4][0], a45, b0l) PKFMA_LO(acc2[4][1], a45, b0h)     \
            PKFMA_LO(acc2[4][2], a45, b1l) PKFMA_LO(acc2[4][3], a45, b1h)     \
            PKFMA_HI(acc2[5][0], a45, b0l) PKFMA_HI(acc2[5][1], a45, b0h)     \
            PKFMA_HI(acc2[5][2], a45, b1l) PKFMA_HI(acc2[5][3], a45, b1h)     \
            PKFMA_LO(acc2[6][0], a67, b0l) PKFMA_LO(acc2[6][1], a67, b0h)     \
            PKFMA_LO(acc2[6][2], a67, b1l) PKFMA_LO(acc2[6][3], a67, b1h)     \
            PKFMA_HI(acc2[7][0], a67, b0l) PKFMA_HI(acc2[7][1], a67, b0h)     \
            PKFMA_HI(acc2[7][2], a67, b1l) PKFMA_HI(acc2[7][3], a67, b1h)     \
        }

    for (int kt = 0; kt < 16; ++kt) {
        const float* acur = a_s + (kt & 1) * ABUF3;
        const float* bcur = b_s + (kt & 1) * BBUF3;
        float* anx = a_s + ((kt & 1) ^ 1) * ABUF3;
        float* bnx = b_s + ((kt & 1) ^ 1) * BBUF3;
        const bool pf = (kt < 15);

        v4f B0, B1, B2, B3, A0;
        if (pf) {            // issue next-slice loads; latency hides under kk0-9
            const float* nb = bsrc + (kt + 1) * 16;
            B0 = *(const v4f*)(nb + (size_t)0 * 64 * D_);
            B1 = *(const v4f*)(nb + (size_t)1 * 64 * D_);
            B2 = *(const v4f*)(nb + (size_t)2 * 64 * D_);
            B3 = *(const v4f*)(nb + (size_t)3 * 64 * D_);
            A0 = *(const v4f*)(asrc + (kt + 1) * 16);
        }
        FMA_RANGE(0, 10)
        if (pf) {            // writes to the other buffer: no barrier needed here
            #pragma unroll
            for (int j = 0; j < 4; ++j) {
                bnx[bwoff + j * BSTR2 + 0 * 64] = B0[j];
                bnx[bwoff + j * BSTR2 + 1 * 64] = B1[j];
                bnx[bwoff + j * BSTR2 + 2 * 64] = B2[j];
                bnx[bwoff + j * BSTR2 + 3 * 64] = B3[j];
            }
            v4f wb = *(const v4f*)(wbar_s + (kt + 1) * 16 + aq * 4);
            anx[awoff + 0 * ASTR3] = A0[0] * wb[0];
            anx[awoff + 1 * ASTR3] = A0[1] * wb[1];
            anx[awoff + 2 * ASTR3] = A0[2] * wb[2];
            anx[awoff + 3 * ASTR3] = A0[3] * wb[3];
        }
        FMA_RANGE(10, 16)
        __syncthreads();     // publishes buf^1 writes; retires buf readers
    }
    #undef FMA_RANGE

    // write 8 rows x 8 cols (2x b128 per row; quarter-wave-contiguous 256B)
    #pragma unroll
    for (int j = 0; j < 8; ++j) {
        float* wrow = ws + ((size_t)bt * C_ + c0 + wr + rg * 8 + j) * C_ + n0;
        v4f o0 = __builtin_shufflevector(acc2[j][0], acc2[j][1], 0, 1, 2, 3);
        v4f o1 = __builtin_shufflevector(acc2[j][2], acc2[j][3], 0, 1, 2, 3);
        *(v4f*)(wrow + bbase)      = o0;
        *(v4f*)(wrow + bbase + 64) = o1;
    }
}

// ========================== Kernel 2: epilogue ===========================
extern "C" __global__ __launch_bounds__(256, 2)
void epilogue_k(const float* __restrict__ ws,
                const int* __restrict__ cmask,
                const float* __restrict__ mu_g,
                const float* __restrict__ pr_g,
                float* __restrict__ out)
{
    const int tid  = threadIdx.x;
    const int lane = tid & 63;
    const int wv   = tid >> 6;

    const int blk = blockIdx.x;
    const int bt  = blk >> 7;          // 0..31
    const int rq  = blk & 127;         // 4-row group
    const int b   = bt >> 3;

    // zero this block's output slice (fire-and-forget; drained at the barrier
    // below, covered by the top-k compute)
    {
        const float4 z = make_float4(0.f, 0.f, 0.f, 0.f);
        #pragma unroll
        for (int ks = 0; ks < KS_; ++ks) {
            float* ob = out + ((size_t)(bt * KS_ + ks) * C_ + rq * 4) * C_;
            *(float4*)(ob + (size_t)tid * 4)         = z;
            *(float4*)(ob + (size_t)(tid + 256) * 4) = z;
        }
    }

    const int c  = rq * 4 + wv;        // this wave's row
    const int vr = cmask[b * C_ + c];

    float row[8];
    {
        const float* wrow = ws + ((size_t)bt * C_ + c) * C_ + lane * 8;
        float4 r0 = *(const float4*)wrow;
        float4 r1 = *(const float4*)(wrow + 4);
        row[0] = r0.x; row[1] = r0.y; row[2] = r0.z; row[3] = r0.w;
        row[4] = r1.x; row[5] = r1.y; row[6] = r1.z; row[7] = r1.w;
        int4 m0 = *(const int4*)(cmask + b * C_ + lane * 8);
        int4 m1 = *(const int4*)(cmask + b * C_ + lane * 8 + 4);
        int em[8] = {m0.x, m0.y, m0.z, m0.w, m1.x, m1.y, m1.z, m1.w};
        #pragma unroll
        for (int i = 0; i < 8; ++i) {
            bool ok = (vr > 0) && (em[i] > 0);
            row[i] = ok ? row[i] : -NEG;
        }
    }

    float tv[TOPK_];
    int   te[TOPK_];
    unsigned int taken = 0;
    #pragma unroll
    for (int j = 0; j < TOPK_; ++j) {
        float lv = -3.3e38f;
        int   li = 0;
        #pragma unroll
        for (int i = 0; i < 8; ++i) {
            bool better = (!((taken >> i) & 1u)) && (row[i] > lv);
            lv = better ? row[i] : lv;
            li = better ? i : li;
        }
        int le = lane * 8 + li;
        #pragma unroll
        for (int off = 1; off < 64; off <<= 1) {
            float ov = __shfl_xor(lv, off);
            int   oe = __shfl_xor(le, off);
            bool take = (ov > lv) || (ov == lv && oe < le);
            lv = take ? ov : lv;
            le = take ? oe : le;
        }
        tv[j] = lv;
        te[j] = le;
        if ((le >> 3) == lane) taken |= 1u << (le & 7);
    }
    const float mx = tv[0];
    float ssum = 0.f;
    #pragma unroll
    for (int j = 0; j < TOPK_; ++j) ssum += expf(tv[j] - mx);

    float oval = 0.f;
    size_t ooff = 0;
    {
        const int ksq = (lane < 40) ? (lane / 10) : 3;
        const int myj = (lane < 40) ? (lane - (lane / 10) * 10) : 0;
        const float mu = mu_g[ksq];
        const float pr = pr_g[ksq];
        float sps = 0.f, spj = 0.f, tvj = 0.f;
        int ej = 0;
        #pragma unroll
        for (int j = 0; j < TOPK_; ++j) {
            float d = fabsf((float)(te[j] - c));
            d = fminf(d, 160.f) * (1.0f / 160.0f);
            float x  = d - mu;
            float sp = expf(-0.5f * x * x * pr * pr);
            sps += sp;
            if (j == myj) { spj = sp; tvj = tv[j]; ej = te[j]; }
        }
        oval = (expf(tvj - mx) / ssum) * (spj / sps);
        ooff = ((size_t)(bt * KS_ + ksq) * C_ + c) * C_ + ej;
    }

    __syncthreads();   // drain zero-stores (overlapped by compute above)
    if (lane < 40) out[ooff] = oval;
}

// ===================== Fallback: fused kernel (R6) =======================
#define BSTR 516
extern "C" __global__ __launch_bounds__(256, 2)
void graph_learner(const float* __restrict__ ctx,
                   const int* __restrict__ cmask,
                   const float* __restrict__ W,
                   const float* __restrict__ mu_g,
                   const float* __restrict__ pr_g,
                   float* __restrict__ out)
{
    __shared__ __align__(16) float wbar_s[D_];
    __shared__ __align__(16) float a_s[16 * ASTR];
    __shared__ __align__(16) float b_s[16 * BSTR];
    __shared__ __align__(8)  float res_s[2560];
    __shared__ unsigned int vmask_s[16];

    const int tid  = threadIdx.x;
    const int lane = tid & 63;
    const int wv   = tid >> 6;
    const int w8   = wv * 8;

    const int blk = blockIdx.x;
    const int bt  = (blk & 7) * 4 + ((blk >> 3) & 3);
    const int c0  = (blk >> 5) * 32;
    const int b   = bt >> 3;

    const float* ctx_bt = ctx + (size_t)bt * (C_ * D_);
    const int*   mask_b = cmask + b * C_;

    {
        float w0 = W[tid], w1 = W[D_ + tid], w2 = W[2 * D_ + tid], w3 = W[3 * D_ + tid];
        wbar_s[tid] = 0.25f * (fmaxf(w0, 0.f) + fmaxf(w1, 0.f) + fmaxf(w2, 0.f) + fmaxf(w3, 0.f));
    }
    if (tid < 16) {
        unsigned int m = 0;
        for (int i = 0; i < 32; ++i)
            m |= (mask_b[tid * 32 + i] > 0 ? 1u : 0u) << i;
        vmask_s[tid] = m;
    }

    const int brow = tid >> 2;
    const int bq   = tid & 3;
    const float* bsrc = ctx_bt + (size_t)brow * D_ + bq * 4;
    const int bwbase = (4 * bq) * BSTR + 4 * csw2(brow >> 2) + (brow & 3);
    const int ar_ = tid >> 2;
    const int aq  = tid & 3;
    const float* asrc = ctx_bt + (size_t)(c0 + ar_) * D_ + aq * 4;
    const int awbase = (4 * aq) * ASTR + ar_;
    const int bc0 = 4 * csw2(2 * lane);
    const int bc1 = 4 * csw2(2 * lane + 1);

    v2f acc2[8][4];
    #pragma unroll
    for (int j = 0; j < 8; ++j)
        #pragma unroll
        for (int t = 0; t < 4; ++t) acc2[j][t] = (v2f){0.f, 0.f};

    for (int kt = 0; kt < 16; ++kt) {
        __syncthreads();
        #pragma unroll
        for (int i = 0; i < 8; ++i) {
            float4 v = *(const float4*)(bsrc + (size_t)i * 64 * D_ + kt * 16);
            b_s[bwbase + 0 * BSTR + i * 64] = v.x;
            b_s[bwbase + 1 * BSTR + i * 64] = v.y;
            b_s[bwbase + 2 * BSTR + i * 64] = v.z;
            b_s[bwbase + 3 * BSTR + i * 64] = v.w;
        }
        if (tid < 128) {
            float4 v  = *(const float4*)(asrc + kt * 16);
            float4 wb = *(const float4*)(wbar_s + kt * 16 + aq * 4);
            a_s[awbase + 0 * ASTR] = v.x * wb.x;
            a_s[awbase + 1 * ASTR] = v.y * wb.y;
            a_s[awbase + 2 * ASTR] = v.z * wb.z;
            a_s[awbase + 3 * ASTR] = v.w * wb.w;
        }
        __syncthreads();
        #pragma unroll
        for (int kk = 0; kk < 16; ++kk) {
            float4 av0 = *(const float4*)(a_s + kk * ASTR + w8);
            float4 av1 = *(const float4*)(a_s + kk * ASTR + w8 + 4);
            float4 bv0 = *(const float4*)(b_s + kk * BSTR + bc0);
            float4 bv1 = *(const float4*)(b_s + kk * BSTR + bc1);
            v2f b20 = (v2f){bv0.x, bv0.y};
            v2f b21 = (v2f){bv0.z, bv0.w};
            v2f b22 = (v2f){bv1.x, bv1.y};
            v2f b23 = (v2f){bv1.z, bv1.w};
            float ar8[8] = {av0.x, av0.y, av0.z, av0.w, av1.x, av1.y, av1.z, av1.w};
            #pragma unroll
            for (int j = 0; j < 8; ++j) {
                v2f a2 = (v2f){ar8[j], ar8[j]};
                asm("v_pk_fma_f32 %0, %1, %2, %0" : "+v"(acc2[j][0]) : "v"(a2), "v"(b20));
                asm("v_pk_fma_f32 %0, %1, %2, %0" : "+v"(acc2[j][1]) : "v"(a2), "v"(b21));
                asm("v_pk_fma_f32 %0, %1, %2, %0" : "+v"(acc2[j][2]) : "v"(a2), "v"(b22));
                asm("v_pk_fma_f32 %0, %1, %2, %0" : "+v"(acc2[j][3]) : "v"(a2), "v"(b23));
            }
        }
    }

    {
        const float4 z = make_float4(0.f, 0.f, 0.f, 0.f);
        #pragma unroll
        for (int ks = 0; ks < KS_; ++ks) {
            float* ob = out + ((size_t)(bt * KS_ + ks) * C_ + c0) * C_;
            #pragma unroll
            for (int i = 0; i < 16; ++i)
                *(float4*)(ob + (size_t)(tid + i * 256) * 4) = z;
        }
    }

    const unsigned int em8 = (vmask_s[lane >> 2] >> ((lane & 3) * 8)) & 0xffu;
    const float mu0 = mu_g[0], mu1 = mu_g[1], mu2 = mu_g[2], mu3 = mu_g[3];
    const float pr0 = pr_g[0], pr1 = pr_g[1], pr2 = pr_g[2], pr3 = pr_g[3];

    #pragma unroll
    for (int jr = 0; jr < 8; ++jr) {
        const int c  = c0 + w8 + jr;
        const int vr = mask_b[c];
        float row[8];
        #pragma unroll
        for (int t = 0; t < 4; ++t) { row[2 * t] = acc2[jr][t].x; row[2 * t + 1] = acc2[jr][t].y; }
        #pragma unroll
        for (int i = 0; i < 8; ++i) {
            bool ok = (vr > 0) && ((em8 >> i) & 1u);
            row[i] = ok ? row[i] : -NEG;
        }
        float tv[TOPK_];
        int   te[TOPK_];
        unsigned int taken = 0;
        #pragma unroll
        for (int j = 0; j < TOPK_; ++j) {
            float lv = -3.3e38f;
            int   li = 0;
            #pragma unroll
            for (int i = 0; i < 8; ++i) {
                bool better = (!((taken >> i) & 1u)) && (row[i] > lv);
                lv = better ? row[i] : lv;
                li = better ? i : li;
            }
            int le = lane * 8 + li;
            #pragma unroll
            for (int off = 1; off < 64; off <<= 1) {
                float ov = __shfl_xor(lv, off);
                int   oe = __shfl_xor(le, off);
                bool take = (ov > lv) || (ov == lv && oe < le);
                lv = take ? ov : lv;
                le = take ? oe : le;
            }
            tv[j] = lv;
            te[j] = le;
            if ((le >> 3) == lane) taken |= 1u << (le & 7);
        }
        const float mx = tv[0];
        float ssum = 0.f;
        #pragma unroll
        for (int j = 0; j < TOPK_; ++j) ssum += expf(tv[j] - mx);

        if (lane < 40) {
            const int ksq = lane / 10;
            const int myj = lane - ksq * 10;
            const float mu = (ksq == 0) ? mu0 : (ksq == 1) ? mu1 : (ksq == 2) ? mu2 : mu3;
            const float pr = (ksq == 0) ? pr0 : (ksq == 1) ? pr1 : (ksq == 2) ? pr2 : pr3;
            float sps = 0.f, spj = 0.f, tvj = 0.f;
            int ej = 0;
            #pragma unroll
            for (int j = 0; j < TOPK_; ++j) {
                float d = fabsf((float)(te[j] - c));
                d = fminf(d, 160.f) * (1.0f / 160.0f);
                float x  = d - mu;
                float sp = expf(-0.5f * x * x * pr * pr);
                sps += sp;
                if (j == myj) { spj = sp; tvj = tv[j]; ej = te[j]; }
            }
            float val = (expf(tvj - mx) / ssum) * (spj / sps);
            int   off = ((bt * KS_ + ksq) * C_ + c) * C_ + ej;
            int   slot = (((wv * 8 + jr) * 40) + lane) * 2;
            res_s[slot]     = val;
            res_s[slot + 1] = __int_as_float(off);
        }
    }

    __syncthreads();
    #pragma unroll
    for (int i = 0; i < 5; ++i) {
        int p = tid * 5 + i;
        float v   = res_s[2 * p];
        int   off = __float_as_int(res_s[2 * p + 1]);
        out[off] = v;
    }
}

extern "C" void kernel_launch(void* const* d_in, const int* in_sizes, int n_in,
                              void* d_out, int out_size, void* d_ws, size_t ws_size,
                              hipStream_t stream) {
    (void)in_sizes; (void)n_in; (void)out_size;
    const float* ctx   = (const float*)d_in[0];
    const int*   cmask = (const int*)d_in[1];
    const float* W     = (const float*)d_in[2];
    const float* mu    = (const float*)d_in[3];
    const float* pr    = (const float*)d_in[4];
    const size_t WS_NEEDED = (size_t)32 * C_ * C_ * sizeof(float);   // 33.5 MB
    if (ws_size >= WS_NEEDED) {
        float* ws = (float*)d_ws;
        gemm_attn<<<dim3(512), dim3(256), 0, stream>>>(ctx, W, ws);
        epilogue_k<<<dim3(4096), dim3(256), 0, stream>>>(ws, cmask, mu, pr, (float*)d_out);
    } else {
        graph_learner<<<dim3(512), dim3(256), 0, stream>>>(ctx, cmask, W, mu, pr, (float*)d_out);
    }
}

// Round 12
// 94.473 us; speedup vs baseline: 1.0319x; 1.0056x over previous
//
#include <hip/hip_runtime.h>
#include <math.h>

#define C_ 512
#define D_ 256
#define KS_ 4
#define TOPK_ 10
#define NEG 1e20f

typedef float v2f __attribute__((ext_vector_type(2)));
typedef float v4f __attribute__((ext_vector_type(4)));

__device__ __forceinline__ int csw2(int g) { return g ^ ((g >> 3) & 1); }

#define ASTR 36     // fused-kernel a_s stride
#define ASTR3 68    // gemm a_s stride: %4==0 -> b128 aligned; 68%32=4 -> staged writes 2-way
#define BSTR2 260   // gemm b_s stride: %4==0 -> b128 aligned; 260%32=4 -> staged writes 2-way
#define ABUF3 (16 * ASTR3)
#define BBUF3 (16 * BSTR2)

// pk-FMA with A-half broadcast via op_sel. Each 32-bit half is an independent
// IEEE fp32 FMA chain -> kk-sequential accumulation stays bit-exact.
#define PKFMA_LO(ACC, AP, BP) \
    asm("v_pk_fma_f32 %0, %1, %2, %0 op_sel:[0,0,0] op_sel_hi:[0,1,1]" \
        : "+v"(ACC) : "v"(AP), "v"(BP));
#define PKFMA_HI(ACC, AP, BP) \
    asm("v_pk_fma_f32 %0, %1, %2, %0 op_sel:[1,0,0] op_sel_hi:[1,1,1]" \
        : "+v"(ACC) : "v"(AP), "v"(BP));

// ============================ Kernel 1: GEMM =============================
// attention[bt][c][e] -> ws. Tile 64x256, grid 512, 8x8 acc (R11 schedule).
// NEW: background-zeroes the entire `out` buffer (4 float4/thread/kt) using
// the gemm's idle HBM-write bandwidth; stores issued after prefetch loads so
// the ds_write vmcnt wait doesn't include them, drained per-kt by the barrier
// ~600 cyc after issue. Epilogue kernel no longer zeroes.
extern "C" __global__ __launch_bounds__(256, 2)
void gemm_attn(const float* __restrict__ ctx,
               const float* __restrict__ W,
               float* __restrict__ ws,
               float* __restrict__ out)
{
    __shared__ __align__(16) float wbar_s[D_];
    __shared__ __align__(16) float a_s[2 * ABUF3];    // dbuf [kk][row 0..63] (x wbar)
    __shared__ __align__(16) float b_s[2 * BBUF3];    // dbuf [kk][col 0..255]

    const int tid  = threadIdx.x;
    const int lane = tid & 63;
    const int wv   = tid >> 6;
    const int wr   = (wv >> 1) * 32;     // wave row base (0/32)
    const int wc   = (wv & 1) * 128;     // wave col base (0/128)
    const int rg   = lane >> 4;          // row-group 0..3
    const int cg   = lane & 15;          // col-group 0..15

    // XCD swizzle: the 16 tiles of one ctx[b,t] panel land on one XCD's L2
    const int blk  = blockIdx.x;
    const int bt   = (blk & 7) * 4 + ((blk >> 3) & 3);   // 0..31
    const int tile = blk >> 5;                           // 0..15
    const int c0   = (tile & 7) * 64;                    // row tile
    const int n0   = (tile >> 3) * 256;                  // col tile

    const float* ctx_bt = ctx + (size_t)bt * (C_ * D_);
    // this block's 65536-float zero chunk of out (512 blocks cover all 33.5M)
    float* zbase = out + (size_t)blk * 65536 + (size_t)tid * 4;

    // wbar = mean_p relu(W[p,:])
    {
        float w0 = W[tid], w1 = W[D_ + tid], w2 = W[2 * D_ + tid], w3 = W[3 * D_ + tid];
        wbar_s[tid] = 0.25f * (fmaxf(w0, 0.f) + fmaxf(w1, 0.f) + fmaxf(w2, 0.f) + fmaxf(w3, 0.f));
    }

    // staging geometry (coalesced 64B 4-lane groups)
    const int bcol = tid >> 2;           // 0..63; +i*64, i=0..3
    const int bq   = tid & 3;
    const float* bsrc = ctx_bt + (size_t)(n0 + bcol) * D_ + bq * 4;
    const int bwoff = (4 * bq) * BSTR2 + bcol;
    const int ar_ = tid >> 2;
    const int aq  = tid & 3;
    const float* asrc = ctx_bt + (size_t)(c0 + ar_) * D_ + aq * 4;
    const int awoff = (4 * aq) * ASTR3 + ar_;
    const int abase = wr + rg * 8;
    const int bbase = wc + cg * 4;       // quad 0; quad 1 at +64

    __syncthreads();   // wbar ready

    // prologue: stage slice 0 -> buffer 0
    {
        v4f B0 = *(const v4f*)(bsrc + (size_t)0 * 64 * D_);
        v4f B1 = *(const v4f*)(bsrc + (size_t)1 * 64 * D_);
        v4f B2 = *(const v4f*)(bsrc + (size_t)2 * 64 * D_);
        v4f B3 = *(const v4f*)(bsrc + (size_t)3 * 64 * D_);
        v4f A0 = *(const v4f*)asrc;
        #pragma unroll
        for (int j = 0; j < 4; ++j) {
            b_s[bwoff + j * BSTR2 + 0 * 64] = B0[j];
            b_s[bwoff + j * BSTR2 + 1 * 64] = B1[j];
            b_s[bwoff + j * BSTR2 + 2 * 64] = B2[j];
            b_s[bwoff + j * BSTR2 + 3 * 64] = B3[j];
        }
        v4f wb = *(const v4f*)(wbar_s + aq * 4);
        a_s[awoff + 0 * ASTR3] = A0[0] * wb[0];
        a_s[awoff + 1 * ASTR3] = A0[1] * wb[1];
        a_s[awoff + 2 * ASTR3] = A0[2] * wb[2];
        a_s[awoff + 3 * ASTR3] = A0[3] * wb[3];
    }
    __syncthreads();

    v2f acc2[8][4];   // [row j][col pair t]: t=0,1 -> bbase..+3 ; t=2,3 -> bbase+64..+67
    #pragma unroll
    for (int j = 0; j < 8; ++j)
        #pragma unroll
        for (int t = 0; t < 4; ++t) acc2[j][t] = (v2f){0.f, 0.f};

    #define FMA_RANGE(K0, K1)                                                 \
        _Pragma("unroll")                                                     \
        for (int kk = (K0); kk < (K1); ++kk) {                                \
            v4f av0 = *(const v4f*)(acur + kk * ASTR3 + abase);               \
            v4f av1 = *(const v4f*)(acur + kk * ASTR3 + abase + 4);           \
            v4f bv0 = *(const v4f*)(bcur + kk * BSTR2 + bbase);               \
            v4f bv1 = *(const v4f*)(bcur + kk * BSTR2 + bbase + 64);          \
            v2f a01 = __builtin_shufflevector(av0, av0, 0, 1);                \
            v2f a23 = __builtin_shufflevector(av0, av0, 2, 3);                \
            v2f a45 = __builtin_shufflevector(av1, av1, 0, 1);                \
            v2f a67 = __builtin_shufflevector(av1, av1, 2, 3);                \
            v2f b0l = __builtin_shufflevector(bv0, bv0, 0, 1);                \
            v2f b0h = __builtin_shufflevector(bv0, bv0, 2, 3);                \
            v2f b1l = __builtin_shufflevector(bv1, bv1, 0, 1);                \
            v2f b1h = __builtin_shufflevector(bv1, bv1, 2, 3);                \
            PKFMA_LO(acc2[0][0], a01, b0l) PKFMA_LO(acc2[0][1], a01, b0h)     \
            PKFMA_LO(acc2[0][2], a01, b1l) PKFMA_LO(acc2[0][3], a01, b1h)     \
            PKFMA_HI(acc2[1][0], a01, b0l) PKFMA_HI(acc2[1][1], a01, b0h)     \
            PKFMA_HI(acc2[1][2], a01, b1l) PKFMA_HI(acc2[1][3], a01, b1h)     \
            PKFMA_LO(acc2[2][0], a23, b0l) PKFMA_LO(acc2[2][1], a23, b0h)     \
            PKFMA_LO(acc2[2][2], a23, b1l) PKFMA_LO(acc2[2][3], a23, b1h)     \
            PKFMA_HI(acc2[3][0], a23, b0l) PKFMA_HI(acc2[3][1], a23, b0h)     \
            PKFMA_HI(acc2[3][2], a23, b1l) PKFMA_HI(acc2[3][3], a23, b1h)     \
            PKFMA_LO(acc2[4][0], a45, b0l) PKFMA_LO(acc2[4][1], a45, b0h)     \
            PKFMA_LO(acc2[4][2], a45, b1l) PKFMA_LO(acc2[4][3], a45, b1h)     \
            PKFMA_HI(acc2[5][0], a45, b0l) PKFMA_HI(acc2[5][1], a45, b0h)     \
            PKFMA_HI(acc2[5][2], a45, b1l) PKFMA_HI(acc2[5][3], a45, b1h)     \
            PKFMA_LO(acc2[6][0], a67, b0l) PKFMA_LO(acc2[6][1], a67, b0h)     \
            PKFMA_LO(acc2[6][2], a67, b1l) PKFMA_LO(acc2[6][3], a67, b1h)     \
            PKFMA_HI(acc2[7][0], a67, b0l) PKFMA_HI(acc2[7][1], a67, b0h)     \
            PKFMA_HI(acc2[7][2], a67, b1l) PKFMA_HI(acc2[7][3], a67, b1h)     \
        }

    const v4f zv = (v4f){0.f, 0.f, 0.f, 0.f};

    for (int kt = 0; kt < 16; ++kt) {
        const float* acur = a_s + (kt & 1) * ABUF3;
        const float* bcur = b_s + (kt & 1) * BBUF3;
        float* anx = a_s + ((kt & 1) ^ 1) * ABUF3;
        float* bnx = b_s + ((kt & 1) ^ 1) * BBUF3;
        const bool pf = (kt < 15);

        v4f B0, B1, B2, B3, A0;
        if (pf) {            // issue next-slice loads; latency hides under kk0-9
            const float* nb = bsrc + (kt + 1) * 16;
            B0 = *(const v4f*)(nb + (size_t)0 * 64 * D_);
            B1 = *(const v4f*)(nb + (size_t)1 * 64 * D_);
            B2 = *(const v4f*)(nb + (size_t)2 * 64 * D_);
            B3 = *(const v4f*)(nb + (size_t)3 * 64 * D_);
            A0 = *(const v4f*)(asrc + (kt + 1) * 16);
        }
        // background zero-stores (AFTER loads: ds_write's counted vmcnt wait
        // excludes them; end-of-kt barrier drains them ~600 cyc later)
        #pragma unroll
        for (int q = 0; q < 4; ++q)
            *(v4f*)(zbase + (size_t)(kt * 4 + q) * 1024) = zv;

        FMA_RANGE(0, 10)
        if (pf) {            // writes to the other buffer: no barrier needed here
            #pragma unroll
            for (int j = 0; j < 4; ++j) {
                bnx[bwoff + j * BSTR2 + 0 * 64] = B0[j];
                bnx[bwoff + j * BSTR2 + 1 * 64] = B1[j];
                bnx[bwoff + j * BSTR2 + 2 * 64] = B2[j];
                bnx[bwoff + j * BSTR2 + 3 * 64] = B3[j];
            }
            v4f wb = *(const v4f*)(wbar_s + (kt + 1) * 16 + aq * 4);
            anx[awoff + 0 * ASTR3] = A0[0] * wb[0];
            anx[awoff + 1 * ASTR3] = A0[1] * wb[1];
            anx[awoff + 2 * ASTR3] = A0[2] * wb[2];
            anx[awoff + 3 * ASTR3] = A0[3] * wb[3];
        }
        FMA_RANGE(10, 16)
        __syncthreads();     // publishes buf^1 writes; retires buf readers; drains zeros
    }
    #undef FMA_RANGE

    // write 8 rows x 8 cols (2x b128 per row)
    #pragma unroll
    for (int j = 0; j < 8; ++j) {
        float* wrow = ws + ((size_t)bt * C_ + c0 + wr + rg * 8 + j) * C_ + n0;
        v4f o0 = __builtin_shufflevector(acc2[j][0], acc2[j][1], 0, 1, 2, 3);
        v4f o1 = __builtin_shufflevector(acc2[j][2], acc2[j][3], 0, 1, 2, 3);
        *(v4f*)(wrow + bbase)      = o0;
        *(v4f*)(wrow + bbase + 64) = o1;
    }
}

// ===================== Kernel 2: epilogue (no zeroing) ====================
// One wave per attention row: load row, mask, top-10, softmax, spatial,
// scatter. `out` already zeroed by gemm_attn (prior kernel on the stream).
extern "C" __global__ __launch_bounds__(256, 2)
void epilogue_k(const float* __restrict__ ws,
                const int* __restrict__ cmask,
                const float* __restrict__ mu_g,
                const float* __restrict__ pr_g,
                float* __restrict__ out)
{
    const int tid  = threadIdx.x;
    const int lane = tid & 63;
    const int wv   = tid >> 6;

    const int blk = blockIdx.x;
    const int bt  = blk >> 7;          // 0..31
    const int rq  = blk & 127;         // 4-row group
    const int b   = bt >> 3;

    const int c  = rq * 4 + wv;        // this wave's row
    const int vr = cmask[b * C_ + c];

    float row[8];
    {
        const float* wrow = ws + ((size_t)bt * C_ + c) * C_ + lane * 8;
        float4 r0 = *(const float4*)wrow;
        float4 r1 = *(const float4*)(wrow + 4);
        row[0] = r0.x; row[1] = r0.y; row[2] = r0.z; row[3] = r0.w;
        row[4] = r1.x; row[5] = r1.y; row[6] = r1.z; row[7] = r1.w;
        int4 m0 = *(const int4*)(cmask + b * C_ + lane * 8);
        int4 m1 = *(const int4*)(cmask + b * C_ + lane * 8 + 4);
        int em[8] = {m0.x, m0.y, m0.z, m0.w, m1.x, m1.y, m1.z, m1.w};
        #pragma unroll
        for (int i = 0; i < 8; ++i) {
            bool ok = (vr > 0) && (em[i] > 0);
            row[i] = ok ? row[i] : -NEG;
        }
    }

    float tv[TOPK_];
    int   te[TOPK_];
    unsigned int taken = 0;
    #pragma unroll
    for (int j = 0; j < TOPK_; ++j) {
        float lv = -3.3e38f;
        int   li = 0;
        #pragma unroll
        for (int i = 0; i < 8; ++i) {
            bool better = (!((taken >> i) & 1u)) && (row[i] > lv);
            lv = better ? row[i] : lv;
            li = better ? i : li;
        }
        int le = lane * 8 + li;
        #pragma unroll
        for (int off = 1; off < 64; off <<= 1) {
            float ov = __shfl_xor(lv, off);
            int   oe = __shfl_xor(le, off);
            bool take = (ov > lv) || (ov == lv && oe < le);
            lv = take ? ov : lv;
            le = take ? oe : le;
        }
        tv[j] = lv;
        te[j] = le;
        if ((le >> 3) == lane) taken |= 1u << (le & 7);
    }
    const float mx = tv[0];
    float ssum = 0.f;
    #pragma unroll
    for (int j = 0; j < TOPK_; ++j) ssum += expf(tv[j] - mx);

    if (lane < 40) {
        const int ksq = lane / 10;
        const int myj = lane - ksq * 10;
        const float mu = mu_g[ksq];
        const float pr = pr_g[ksq];
        float sps = 0.f, spj = 0.f, tvj = 0.f;
        int ej = 0;
        #pragma unroll
        for (int j = 0; j < TOPK_; ++j) {
            float d = fabsf((float)(te[j] - c));
            d = fminf(d, 160.f) * (1.0f / 160.0f);
            float x  = d - mu;
            float sp = expf(-0.5f * x * x * pr * pr);
            sps += sp;
            if (j == myj) { spj = sp; tvj = tv[j]; ej = te[j]; }
        }
        float oval = (expf(tvj - mx) / ssum) * (spj / sps);
        out[((size_t)(bt * KS_ + ksq) * C_ + c) * C_ + ej] = oval;
    }
}

// ===================== Fallback: fused kernel (R6) =======================
#define BSTR 516
extern "C" __global__ __launch_bounds__(256, 2)
void graph_learner(const float* __restrict__ ctx,
                   const int* __restrict__ cmask,
                   const float* __restrict__ W,
                   const float* __restrict__ mu_g,
                   const float* __restrict__ pr_g,
                   float* __restrict__ out)
{
    __shared__ __align__(16) float wbar_s[D_];
    __shared__ __align__(16) float a_s[16 * ASTR];
    __shared__ __align__(16) float b_s[16 * BSTR];
    __shared__ __align__(8)  float res_s[2560];
    __shared__ unsigned int vmask_s[16];

    const int tid  = threadIdx.x;
    const int lane = tid & 63;
    const int wv   = tid >> 6;
    const int w8   = wv * 8;

    const int blk = blockIdx.x;
    const int bt  = (blk & 7) * 4 + ((blk >> 3) & 3);
    const int c0  = (blk >> 5) * 32;
    const int b   = bt >> 3;

    const float* ctx_bt = ctx + (size_t)bt * (C_ * D_);
    const int*   mask_b = cmask + b * C_;

    {
        float w0 = W[tid], w1 = W[D_ + tid], w2 = W[2 * D_ + tid], w3 = W[3 * D_ + tid];
        wbar_s[tid] = 0.25f * (fmaxf(w0, 0.f) + fmaxf(w1, 0.f) + fmaxf(w2, 0.f) + fmaxf(w3, 0.f));
    }
    if (tid < 16) {
        unsigned int m = 0;
        for (int i = 0; i < 32; ++i)
            m |= (mask_b[tid * 32 + i] > 0 ? 1u : 0u) << i;
        vmask_s[tid] = m;
    }

    const int brow = tid >> 2;
    const int bq   = tid & 3;
    const float* bsrc = ctx_bt + (size_t)brow * D_ + bq * 4;
    const int bwbase = (4 * bq) * BSTR + 4 * csw2(brow >> 2) + (brow & 3);
    const int ar_ = tid >> 2;
    const int aq  = tid & 3;
    const float* asrc = ctx_bt + (size_t)(c0 + ar_) * D_ + aq * 4;
    const int awbase = (4 * aq) * ASTR + ar_;
    const int bc0 = 4 * csw2(2 * lane);
    const int bc1 = 4 * csw2(2 * lane + 1);

    v2f acc2[8][4];
    #pragma unroll
    for (int j = 0; j < 8; ++j)
        #pragma unroll
        for (int t = 0; t < 4; ++t) acc2[j][t] = (v2f){0.f, 0.f};

    for (int kt = 0; kt < 16; ++kt) {
        __syncthreads();
        #pragma unroll
        for (int i = 0; i < 8; ++i) {
            float4 v = *(const float4*)(bsrc + (size_t)i * 64 * D_ + kt * 16);
            b_s[bwbase + 0 * BSTR + i * 64] = v.x;
            b_s[bwbase + 1 * BSTR + i * 64] = v.y;
            b_s[bwbase + 2 * BSTR + i * 64] = v.z;
            b_s[bwbase + 3 * BSTR + i * 64] = v.w;
        }
        if (tid < 128) {
            float4 v  = *(const float4*)(asrc + kt * 16);
            float4 wb = *(const float4*)(wbar_s + kt * 16 + aq * 4);
            a_s[awbase + 0 * ASTR] = v.x * wb.x;
            a_s[awbase + 1 * ASTR] = v.y * wb.y;
            a_s[awbase + 2 * ASTR] = v.z * wb.z;
            a_s[awbase + 3 * ASTR] = v.w * wb.w;
        }
        __syncthreads();
        #pragma unroll
        for (int kk = 0; kk < 16; ++kk) {
            float4 av0 = *(const float4*)(a_s + kk * ASTR + w8);
            float4 av1 = *(const float4*)(a_s + kk * ASTR + w8 + 4);
            float4 bv0 = *(const float4*)(b_s + kk * BSTR + bc0);
            float4 bv1 = *(const float4*)(b_s + kk * BSTR + bc1);
            v2f b20 = (v2f){bv0.x, bv0.y};
            v2f b21 = (v2f){bv0.z, bv0.w};
            v2f b22 = (v2f){bv1.x, bv1.y};
            v2f b23 = (v2f){bv1.z, bv1.w};
            float ar8[8] = {av0.x, av0.y, av0.z, av0.w, av1.x, av1.y, av1.z, av1.w};
            #pragma unroll
            for (int j = 0; j < 8; ++j) {
                v2f a2 = (v2f){ar8[j], ar8[j]};
                asm("v_pk_fma_f32 %0, %1, %2, %0" : "+v"(acc2[j][0]) : "v"(a2), "v"(b20));
                asm("v_pk_fma_f32 %0, %1, %2, %0" : "+v"(acc2[j][1]) : "v"(a2), "v"(b21));
                asm("v_pk_fma_f32 %0, %1, %2, %0" : "+v"(acc2[j][2]) : "v"(a2), "v"(b22));
                asm("v_pk_fma_f32 %0, %1, %2, %0" : "+v"(acc2[j][3]) : "v"(a2), "v"(b23));
            }
        }
    }

    {
        const float4 z = make_float4(0.f, 0.f, 0.f, 0.f);
        #pragma unroll
        for (int ks = 0; ks < KS_; ++ks) {
            float* ob = out + ((size_t)(bt * KS_ + ks) * C_ + c0) * C_;
            #pragma unroll
            for (int i = 0; i < 16; ++i)
                *(float4*)(ob + (size_t)(tid + i * 256) * 4) = z;
        }
    }

    const unsigned int em8 = (vmask_s[lane >> 2] >> ((lane & 3) * 8)) & 0xffu;
    const float mu0 = mu_g[0], mu1 = mu_g[1], mu2 = mu_g[2], mu3 = mu_g[3];
    const float pr0 = pr_g[0], pr1 = pr_g[1], pr2 = pr_g[2], pr3 = pr_g[3];

    #pragma unroll
    for (int jr = 0; jr < 8; ++jr) {
        const int c  = c0 + w8 + jr;
        const int vr = mask_b[c];
        float row[8];
        #pragma unroll
        for (int t = 0; t < 4; ++t) { row[2 * t] = acc2[jr][t].x; row[2 * t + 1] = acc2[jr][t].y; }
        #pragma unroll
        for (int i = 0; i < 8; ++i) {
            bool ok = (vr > 0) && ((em8 >> i) & 1u);
            row[i] = ok ? row[i] : -NEG;
        }
        float tv[TOPK_];
        int   te[TOPK_];
        unsigned int taken = 0;
        #pragma unroll
        for (int j = 0; j < TOPK_; ++j) {
            float lv = -3.3e38f;
            int   li = 0;
            #pragma unroll
            for (int i = 0; i < 8; ++i) {
                bool better = (!((taken >> i) & 1u)) && (row[i] > lv);
                lv = better ? row[i] : lv;
                li = better ? i : li;
            }
            int le = lane * 8 + li;
            #pragma unroll
            for (int off = 1; off < 64; off <<= 1) {
                float ov = __shfl_xor(lv, off);
                int   oe = __shfl_xor(le, off);
                bool take = (ov > lv) || (ov == lv && oe < le);
                lv = take ? ov : lv;
                le = take ? oe : le;
            }
            tv[j] = lv;
            te[j] = le;
            if ((le >> 3) == lane) taken |= 1u << (le & 7);
        }
        const float mx = tv[0];
        float ssum = 0.f;
        #pragma unroll
        for (int j = 0; j < TOPK_; ++j) ssum += expf(tv[j] - mx);

        if (lane < 40) {
            const int ksq = lane / 10;
            const int myj = lane - ksq * 10;
            const float mu = (ksq == 0) ? mu0 : (ksq == 1) ? mu1 : (ksq == 2) ? mu2 : mu3;
            const float pr = (ksq == 0) ? pr0 : (ksq == 1) ? pr1 : (ksq == 2) ? pr2 : pr3;
            float sps = 0.f, spj = 0.f, tvj = 0.f;
            int ej = 0;
            #pragma unroll
            for (int j = 0; j < TOPK_; ++j) {
                float d = fabsf((float)(te[j] - c));
                d = fminf(d, 160.f) * (1.0f / 160.0f);
                float x  = d - mu;
                float sp = expf(-0.5f * x * x * pr * pr);
                sps += sp;
                if (j == myj) { spj = sp; tvj = tv[j]; ej = te[j]; }
            }
            float val = (expf(tvj - mx) / ssum) * (spj / sps);
            int   off = ((bt * KS_ + ksq) * C_ + c) * C_ + ej;
            int   slot = (((wv * 8 + jr) * 40) + lane) * 2;
            res_s[slot]     = val;
            res_s[slot + 1] = __int_as_float(off);
        }
    }

    __syncthreads();
    #pragma unroll
    for (int i = 0; i < 5; ++i) {
        int p = tid * 5 + i;
        float v   = res_s[2 * p];
        int   off = __float_as_int(res_s[2 * p + 1]);
        out[off] = v;
    }
}

extern "C" void kernel_launch(void* const* d_in, const int* in_sizes, int n_in,
                              void* d_out, int out_size, void* d_ws, size_t ws_size,
                              hipStream_t stream) {
    (void)in_sizes; (void)n_in; (void)out_size;
    const float* ctx   = (const float*)d_in[0];
    const int*   cmask = (const int*)d_in[1];
    const float* W     = (const float*)d_in[2];
    const float* mu    = (const float*)d_in[3];
    const float* pr    = (const float*)d_in[4];
    const size_t WS_NEEDED = (size_t)32 * C_ * C_ * sizeof(float);   // 33.5 MB
    if (ws_size >= WS_NEEDED) {
        float* ws = (float*)d_ws;
        gemm_attn<<<dim3(512), dim3(256), 0, stream>>>(ctx, W, ws, (float*)d_out);
        epilogue_k<<<dim3(4096), dim3(256), 0, stream>>>(ws, cmask, mu, pr, (float*)d_out);
    } else {
        graph_learner<<<dim3(512), dim3(256), 0, stream>>>(ctx, cmask, W, mu, pr, (float*)d_out);
    }
}